// Round 1
// baseline (1176.205 us; speedup 1.0000x reference)
//
#include <hip/hip_runtime.h>
#include <hip/hip_bf16.h>
#include <stdint.h>

#define B_ 4096
#define D_ 512
#define H_ 2048
#define NS_ 16

typedef __bf16 bf16x8 __attribute__((ext_vector_type(8)));
typedef float f32x4 __attribute__((ext_vector_type(4)));
typedef short short4v __attribute__((ext_vector_type(4)));

__device__ __forceinline__ short f2bf(float f) {
  union { float f; uint32_t u; } c; c.f = f;
  uint32_t u = c.u;
  return (short)((u + 0x7fffu + ((u >> 16) & 1u)) >> 16);
}

__device__ __forceinline__ float tanh_fast(float x) {
  float e = __expf(2.0f * x);
  return 1.0f - 2.0f / (e + 1.0f);   // exp overflow -> 1, underflow -> -1 : safe
}

__device__ __forceinline__ void gload16(const void* g, void* l) {
  __builtin_amdgcn_global_load_lds((const __attribute__((address_space(1))) void*)g,
                                   (__attribute__((address_space(3))) void*)l,
                                   16, 0, 0);
}

// ---------------------------------------------------------------------------
// C = A @ Bt^T  where A is [M][K] bf16 row-major, Bt is [N][K] bf16 row-major.
// EPI 0: outf[row*ldN+col] = acc + bias[col]              (xproj build)
// EPI 1: col<H : outh = bf16(tanh(xproj + acc))           (fused step)
//        col>=H: outf[row*NS*D + tout*D + col-H] = acc + bias[col-H]
// EPI 2: outf[row*NS*D + tout*D + col] = acc + bias[col]  (final out GEMM)
// ---------------------------------------------------------------------------
template<int BM, int BN, int EPI>
__global__ __launch_bounds__(256, 2) void gemm_bt(
    const short* __restrict__ A, const short* __restrict__ Bt, int K,
    const float* __restrict__ xproj, const float* __restrict__ bias,
    float* __restrict__ outf, short* __restrict__ outh, int ldN, int tout)
{
  constexpr int WM = BM / 2, WN = BN / 2;
  constexpr int RM = WM / 16, RN = WN / 16;
  __shared__ short lds[2][(BM + BN) * 32];
  const int tid = threadIdx.x, lane = tid & 63, wid = tid >> 6;
  const int wm = wid >> 1, wn = wid & 1;
  const int row0 = blockIdx.y * BM, col0 = blockIdx.x * BN;
  const short* Ag = A + (size_t)row0 * K;
  const short* Bg = Bt + (size_t)col0 * K;

  f32x4 acc[RM][RN];
#pragma unroll
  for (int m = 0; m < RM; ++m)
#pragma unroll
    for (int n = 0; n < RN; ++n)
      acc[m][n] = (f32x4){0.f, 0.f, 0.f, 0.f};

  const int nt = K >> 5;

  auto stage = [&](int kt, int buf) {
    const short* ga = Ag + (kt << 5);
#pragma unroll
    for (int i = 0; i < BM * 4; i += 256) {
      int slot = i + tid;
      gload16(ga + (size_t)(slot >> 2) * K + ((slot & 3) << 3), &lds[buf][slot * 8]);
    }
    const short* gb = Bg + (kt << 5);
#pragma unroll
    for (int i = 0; i < BN * 4; i += 256) {
      int slot = i + tid;
      gload16(gb + (size_t)(slot >> 2) * K + ((slot & 3) << 3),
              &lds[buf][BM * 32 + slot * 8]);
    }
  };

  stage(0, 0);
  __syncthreads();
  int cur = 0;
  const int kq = (lane >> 4) << 3;
  const int rr = lane & 15;
  for (int kt = 0; kt < nt; ++kt) {
    if (kt + 1 < nt) stage(kt + 1, cur ^ 1);
    const short* la = &lds[cur][(wm * WM) * 32];
    const short* lb = &lds[cur][BM * 32 + (wn * WN) * 32];
    bf16x8 a[RM], b[RN];
#pragma unroll
    for (int m = 0; m < RM; ++m)
      a[m] = *(const bf16x8*)(la + (m * 16 + rr) * 32 + kq);
#pragma unroll
    for (int n = 0; n < RN; ++n)
      b[n] = *(const bf16x8*)(lb + (n * 16 + rr) * 32 + kq);
#pragma unroll
    for (int m = 0; m < RM; ++m)
#pragma unroll
      for (int n = 0; n < RN; ++n)
        acc[m][n] = __builtin_amdgcn_mfma_f32_16x16x32_bf16(a[m], b[n], acc[m][n], 0, 0, 0);
    __syncthreads();
    cur ^= 1;
  }

  // epilogue: C/D layout col = lane&15, row = (lane>>4)*4 + reg   [m89-verified]
  const int rb = row0 + wm * WM + ((lane >> 4) << 2);
  const int cb = col0 + wn * WN + (lane & 15);
#pragma unroll
  for (int m = 0; m < RM; ++m) {
#pragma unroll
    for (int n = 0; n < RN; ++n) {
      const int col = cb + n * 16;
#pragma unroll
      for (int r = 0; r < 4; ++r) {
        const int row = rb + m * 16 + r;
        float v = acc[m][n][r];
        if (EPI == 0) {
          outf[(size_t)row * ldN + col] = v + bias[col];
        } else if (EPI == 2) {
          outf[(size_t)row * (NS_ * D_) + tout * D_ + col] = v + bias[col];
        } else {
          if (col < H_) {
            float x = xproj[(size_t)row * H_ + col];
            outh[(size_t)row * H_ + col] = f2bf(tanh_fast(x + v));
          } else {
            int oc = col - H_;
            outf[(size_t)row * (NS_ * D_) + tout * D_ + oc] = v + bias[oc];
          }
        }
      }
    }
  }
}

// in [R][C] fp32  ->  out [C][R] bf16
__global__ void transpose_cvt(const float* __restrict__ in, short* __restrict__ out,
                              int R, int C) {
  __shared__ float tile[32][33];
  const int tx = threadIdx.x & 31, ty = threadIdx.x >> 5;
  const int c0 = blockIdx.x * 32, r0 = blockIdx.y * 32;
#pragma unroll
  for (int i = 0; i < 32; i += 8)
    tile[ty + i][tx] = in[(size_t)(r0 + ty + i) * C + c0 + tx];
  __syncthreads();
#pragma unroll
  for (int i = 0; i < 32; i += 8)
    out[(size_t)(c0 + ty + i) * R + r0 + tx] = f2bf(tile[tx][ty + i]);
}

__global__ void cvt_bf16_k(const float4* __restrict__ in, short4v* __restrict__ out, int n4) {
  int i = blockIdx.x * 256 + threadIdx.x;
  if (i >= n4) return;
  float4 v = in[i];
  short4v o;
  o[0] = f2bf(v.x); o[1] = f2bf(v.y); o[2] = f2bf(v.z); o[3] = f2bf(v.w);
  out[i] = o;
}

__global__ void tanh_h0_k(const float4* __restrict__ xp, short4v* __restrict__ h, int n4) {
  int i = blockIdx.x * 256 + threadIdx.x;
  if (i >= n4) return;
  float4 v = xp[i];
  short4v o;
  o[0] = f2bf(tanh_fast(v.x)); o[1] = f2bf(tanh_fast(v.y));
  o[2] = f2bf(tanh_fast(v.z)); o[3] = f2bf(tanh_fast(v.w));
  h[i] = o;
}

extern "C" void kernel_launch(void* const* d_in, const int* in_sizes, int n_in,
                              void* d_out, int out_size, void* d_ws, size_t ws_size,
                              hipStream_t stream) {
  const float* z    = (const float*)d_in[0];
  const float* Wx   = (const float*)d_in[1];
  const float* Wh   = (const float*)d_in[2];
  const float* bh   = (const float*)d_in[3];
  const float* Wout = (const float*)d_in[4];
  const float* bout = (const float*)d_in[5];
  float* out = (float*)d_out;

  // workspace layout (~84 MB)
  short* zb    = (short*)d_ws;                     // B*D bf16
  short* WxT   = zb + (size_t)B_ * D_;             // [H][D]
  short* WcatT = WxT + (size_t)H_ * D_;            // [H+D][H]  (WhT then WoutT)
  short* WoutT = WcatT + (size_t)H_ * H_;
  short* h0    = WcatT + (size_t)(H_ + D_) * H_;   // [B][H] bf16
  short* h1    = h0 + (size_t)B_ * H_;
  float* xproj = (float*)(h1 + (size_t)B_ * H_);   // [B][H] fp32

  cvt_bf16_k<<<(B_ * D_ / 4 + 255) / 256, 256, 0, stream>>>((const float4*)z, (short4v*)zb, B_ * D_ / 4);
  transpose_cvt<<<dim3(H_ / 32, D_ / 32), 256, 0, stream>>>(Wx, WxT, D_, H_);
  transpose_cvt<<<dim3(H_ / 32, H_ / 32), 256, 0, stream>>>(Wh, WcatT, H_, H_);
  transpose_cvt<<<dim3(D_ / 32, H_ / 32), 256, 0, stream>>>(Wout, WoutT, H_, D_);

  // xproj = z @ Wx + bh
  gemm_bt<128, 128, 0><<<dim3(H_ / 128, B_ / 128), 256, 0, stream>>>(
      zb, WxT, D_, nullptr, bh, xproj, nullptr, H_, 0);
  // h1 = tanh(xproj + 0)
  tanh_h0_k<<<(B_ * H_ / 4 + 255) / 256, 256, 0, stream>>>((const float4*)xproj, (short4v*)h0, B_ * H_ / 4);

  short* hb[2] = {h0, h1};
  for (int t = 1; t <= 15; ++t) {
    const short* hp = hb[(t - 1) & 1];
    short* hn = hb[t & 1];
    // fused: [h_{t+1} | out_{t-1}] = h_t @ [Wh | Wout]
    gemm_bt<128, 128, 1><<<dim3((H_ + D_) / 128, B_ / 128), 256, 0, stream>>>(
        hp, WcatT, H_, xproj, bout, out, hn, 0, t - 1);
  }
  // out_15 = h16 @ Wout + bout
  gemm_bt<128, 64, 2><<<dim3(D_ / 64, B_ / 128), 256, 0, stream>>>(
      hb[1], WoutT, H_, nullptr, bout, out, nullptr, 0, 15);
}